// Round 11
// baseline (200.494 us; speedup 1.0000x reference)
//
#include <hip/hip_runtime.h>

#define DEV __device__ __forceinline__

typedef _Float16 f16x8 __attribute__((ext_vector_type(8)));
typedef float f32x4 __attribute__((ext_vector_type(4)));
typedef unsigned int u32x4 __attribute__((ext_vector_type(4)));

// Closed-form uniform cubic B-spline (knots (j-3)*0.4-1), verified vs Cox-de Boor (R9).
// All KAN-layer inputs are >= 0, so B_0,B_1 == 0. Record: [silu, B_2..B_7, 0].
DEV f16x8 kan_feats8(float x) {
    const float sil = x / (1.0f + __expf(-x));
    const float k0 = (float)(-3) * 0.4f - 1.0f;
    const float t = (x - k0) * 2.5f;
    const float mf = floorf(t);
    const int m = (int)mf;
    const float u = t - mf, v = 1.0f - u;
    const float u2 = u * u, u3 = u2 * u;
    const float N0 = v * v * v * (1.0f / 6.0f);
    const float N1 = (3.0f * u3 - 6.0f * u2 + 4.0f) * (1.0f / 6.0f);
    const float N2 = (-3.0f * u3 + 3.0f * u2 + 3.0f * u + 1.0f) * (1.0f / 6.0f);
    const float N3 = u3 * (1.0f / 6.0f);
    f16x8 g;
    g[0] = (_Float16)sil;
#pragma unroll
    for (int jj = 0; jj < 6; ++jj) {
        const int j = jj + 2;
        float val = 0.0f;
        val = (m == j + 3) ? N0 : val;
        val = (m == j + 2) ? N1 : val;
        val = (m == j + 1) ? N2 : val;
        val = (m == j)     ? N3 : val;
        g[1 + jj] = (_Float16)val;
    }
    g[7] = (_Float16)0.0f;
    return g;
}

// Full 9-feature version (head path).
DEV void kan_feats9(float x, float* f) {
    f[0] = x / (1.0f + __expf(-x));
    const float k0 = (float)(-3) * 0.4f - 1.0f;
    const float t = (x - k0) * 2.5f;
    const float mf = floorf(t);
    const int m = (int)mf;
    const float u = t - mf, v = 1.0f - u;
    const float u2 = u * u, u3 = u2 * u;
    const float N0 = v * v * v * (1.0f / 6.0f);
    const float N1 = (3.0f * u3 - 6.0f * u2 + 4.0f) * (1.0f / 6.0f);
    const float N2 = (-3.0f * u3 + 3.0f * u2 + 3.0f * u + 1.0f) * (1.0f / 6.0f);
    const float N3 = u3 * (1.0f / 6.0f);
#pragma unroll
    for (int j = 0; j < 8; ++j) {
        float val = 0.0f;
        val = (m == j + 3) ? N0 : val;
        val = (m == j + 2) ? N1 : val;
        val = (m == j + 1) ? N2 : val;
        val = (m == j)     ? N3 : val;
        f[1 + j] = val;
    }
}

// LDS A-plane byte offsets (pitch-8 records: one 16B octet per input).
__device__ constexpr int d_l0(int ii) {   // L0: (ci,kh,kw) over 3x7x7
    const int i = ii > 146 ? 146 : ii;    // i=147 zero-weight pad slot
    const int ci = i / 49, rem = i % 49, kh = rem / 7, kw = rem % 7;
    return ((((kw & 1) * 3 + ci) * 13 + kh) * 19 + (kw >> 1)) * 16;
}
__device__ constexpr int d_l1(int i) {    // L1: (ch,kh,kw) over 16x3x3
    const int ch = i / 9, rem = i % 9, kh = rem / 3, kw = rem % 3;
    return ((((kw & 1) * 16 + ch) * 9 + kh) * 5 + (kw >> 1)) * 16;
}

// Reduced weight octet: t=0 base, t=1..6 -> sw[j=t+1]*sc, t=7 = 0.
template <int OUT_F, int IN_F>
DEV void pack_oct8(int g, const float* bw, const float* sw, const float* sc,
                   _Float16* W2) {
    const int o = g % OUT_F, i = g / OUT_F;
    f16x8 v;
    if (i < IN_F) {
        const int wi = o * IN_F + i;
        const float s = sc[wi];
        v[0] = (_Float16)bw[wi];
#pragma unroll
        for (int t = 1; t <= 6; ++t) v[t] = (_Float16)(sw[wi * 8 + t + 1] * s);
        v[7] = (_Float16)0.0f;
    } else {
#pragma unroll
        for (int t = 0; t < 8; ++t) v[t] = (_Float16)0.0f;
    }
    *(f16x8*)(W2 + g * 8) = v;
}

#define PS0 2368   // L0: 148 koct * 16
#define PS1 4608   // L1: 144 koct * 32
#define PS2 18432  // L2: 288 koct * 64
#define PS3 12800  // head
#define PS4 25088  // h2 zero
#define PSUM (PS0 + PS1 + PS2 + PS3 + PS4)

__global__ __launch_bounds__(256) void prep_k(
    const float* __restrict__ bw0, const float* __restrict__ sw0, const float* __restrict__ sc0,
    const float* __restrict__ bw1, const float* __restrict__ sw1, const float* __restrict__ sc1,
    const float* __restrict__ bw2, const float* __restrict__ sw2, const float* __restrict__ sc2,
    const float* __restrict__ bwc, const float* __restrict__ swc, const float* __restrict__ scc,
    _Float16* __restrict__ W2_0, _Float16* __restrict__ W2_1, _Float16* __restrict__ W2_2,
    float* __restrict__ wcT, float* __restrict__ h2, int* __restrict__ cnt) {
    const int e = blockIdx.x * 256 + threadIdx.x;
    if (e < PS0) {
        pack_oct8<16, 147>(e, bw0, sw0, sc0, W2_0);
    } else if (e < PS0 + PS1) {
        pack_oct8<32, 144>(e - PS0, bw1, sw1, sc1, W2_1);
    } else if (e < PS0 + PS1 + PS2) {
        pack_oct8<64, 288>(e - PS0 - PS1, bw2, sw2, sc2, W2_2);
    } else if (e < PS0 + PS1 + PS2 + PS3) {
        const int ee = e - PS0 - PS1 - PS2;
        const int o = ee / 64, i = ee - o * 64;
        const float s = scc[ee];
        wcT[(i * 9 + 0) * 200 + o] = bwc[ee];
#pragma unroll
        for (int t = 0; t < 8; ++t)
            wcT[(i * 9 + 1 + t) * 200 + o] = swc[ee * 8 + t] * s;
    } else if (e < PSUM) {
        h2[e - PS0 - PS1 - PS2 - PS3] = 0.0f;
    } else if (e == PSUM) {
        *cnt = 0;   // conv2 completion counter, re-zeroed every call
    }
}

// L0: featurize-in-block (pitch-8) + 37 MFMA steps + fused relu/2x2 pool -> raw p0.
// LDS 25760 B -> 5 blocks/CU requested for TLP.
__global__ __launch_bounds__(256, 5) void conv0_k(
    const float* __restrict__ x, const _Float16* __restrict__ W2,
    float* __restrict__ p0) {
    __shared__ __align__(16) _Float16 feats[1482 * 8];
    __shared__ float pb[4 * 8 * 16];
    const int tid = threadIdx.x;
    const int vt = blockIdx.x;
    const int b = vt / 196;
    const int r0 = vt - b * 196;
    const int bh = r0 / 7, bw = r0 - (r0 / 7) * 7;
    const int ih0 = bh * 8 - 3, iw0 = bw * 32 - 3;
    for (int t = tid; t < 1482; t += 256) {
        const int iwh = t % 19;
        int r = t / 19;
        const int ihp = r % 13; r /= 13;
        const int ci = r % 3;
        const int par = r / 3;
        const int ih = ih0 + ihp, iw = iw0 + 2 * iwh + par;
        float xv = 0.0f;
        if (ih >= 0 && ih < 224 && iw >= 0 && iw < 224)
            xv = x[((b * 3 + ci) * 224 + ih) * 224 + iw];
        *(f16x8*)(feats + t * 8) = kan_feats8(xv);
    }
    __syncthreads();
    const int lane = tid & 63, mt = tid >> 6;
    const int l15 = lane & 15, q = lane >> 4;
    const bool q1 = q & 1, q2 = q & 2;
    const char* aBase = (const char*)feats + ((2 * mt) * 19 + l15) * 16;
    const f16x8* __restrict__ Wv = (const f16x8*)W2;
    f32x4 acc = {0.f, 0.f, 0.f, 0.f};
#pragma unroll
    for (int s = 0; s < 37; ++s) {
        const int o0 = d_l0(4 * s), o1 = d_l0(4 * s + 1);
        const int o2 = d_l0(4 * s + 2), o3 = d_l0(4 * s + 3);
        const int e01 = q1 ? o1 : o0;
        const int e23 = q1 ? o3 : o2;
        const int aoff = q2 ? e23 : e01;
        const f16x8 a = *(const f16x8*)(aBase + aoff);
        const f16x8 bf = Wv[(s * 4 + q) * 16 + l15];
        acc = __builtin_amdgcn_mfma_f32_16x16x32_f16(a, bf, acc, 0, 0, 0);
    }
    pb[(mt * 8 + 2 * q + 0) * 16 + l15] = fmaxf(fmaxf(acc[0], 0.f), fmaxf(acc[1], 0.f));
    pb[(mt * 8 + 2 * q + 1) * 16 + l15] = fmaxf(fmaxf(acc[2], 0.f), fmaxf(acc[3], 0.f));
    __syncthreads();
    const int pr = tid >> 7, o = (tid >> 3) & 15, wp = tid & 7;
    const float v = fmaxf(pb[((2 * pr) * 8 + wp) * 16 + o],
                          pb[((2 * pr + 1) * 8 + wp) * 16 + o]);
    p0[((b * 16 + o) * 56 + bh * 2 + pr) * 56 + bw * 8 + wp] = v;
}

// L1: featurize-in-block + 36 MFMA steps (wave-pairs split K, LDS reduce) +
// fused relu/pool/featurize -> featP1 (16B records). LDS 27136 B -> 5 blocks/CU.
__global__ __launch_bounds__(256, 5) void conv1_k(
    const float* __restrict__ p0, const _Float16* __restrict__ W2,
    unsigned int* __restrict__ featP1) {
    __shared__ __align__(16) _Float16 feats[1440 * 8];
    __shared__ float abuf[2 * 32 * 16];
    const int tid = threadIdx.x;
    const int vt = blockIdx.x;
    const int b = vt / 49;
    const int r0 = vt - b * 49;
    const int bh = r0 / 7, bw = r0 - (r0 / 7) * 7;
    const int ih0 = bh * 8 - 1, iw0 = bw * 8 - 1;
    for (int t = tid; t < 1296; t += 256) {
        const int iwp = t % 9;
        int r = t / 9;
        const int ihp = r % 9;
        const int ch = r / 9;
        const int ih = ih0 + ihp, iw = iw0 + iwp;
        float xv = 0.0f;
        if (ih >= 0 && ih < 56 && iw >= 0 && iw < 56)
            xv = p0[((b * 16 + ch) * 56 + ih) * 56 + iw];
        const int slot = (((iwp & 1) * 16 + ch) * 9 + ihp) * 5 + (iwp >> 1);
        *(f16x8*)(feats + slot * 8) = kan_feats8(xv);
    }
    __syncthreads();
    const int lane = tid & 63, w = tid >> 6;
    const int kc = w >> 1, ot = w & 1;
    const int l15 = lane & 15, q = lane >> 4;
    const bool q1 = q & 1, q2 = q & 2;
    const int mh = l15 >> 2, mw = l15 & 3;
    const int ocol = ot * 16 + l15;
    const char* aBase = (const char*)feats + ((2 * mh) * 5 + mw) * 16 + kc * 5760;
    const f16x8* __restrict__ Wv = (const f16x8*)W2;
    f32x4 acc = {0.f, 0.f, 0.f, 0.f};
#pragma unroll
    for (int s = 0; s < 18; ++s) {
        const int o0 = d_l1(4 * s), o1 = d_l1(4 * s + 1);
        const int o2 = d_l1(4 * s + 2), o3 = d_l1(4 * s + 3);
        const int e01 = q1 ? o1 : o0;
        const int e23 = q1 ? o3 : o2;
        const int aoff = q2 ? e23 : e01;
        const f16x8 a = *(const f16x8*)(aBase + aoff);
        const f16x8 bf = Wv[(kc * 72 + s * 4 + q) * 32 + ocol];
        acc = __builtin_amdgcn_mfma_f32_16x16x32_f16(a, bf, acc, 0, 0, 0);
    }
#pragma unroll
    for (int reg = 0; reg < 4; ++reg)
        abuf[(kc * 32 + ocol) * 16 + q * 4 + reg] = acc[reg];
    __syncthreads();
    if (tid < 128) {
        const int o = tid >> 2, pp = tid & 3;
        const int hp = pp >> 1, wp = pp & 1;
        float mx = -1e30f;
#pragma unroll
        for (int dh = 0; dh < 2; ++dh)
#pragma unroll
            for (int dw = 0; dw < 2; ++dw) {
                const int m = (2 * hp + dh) * 4 + 2 * wp + dw;
                const float s = abuf[(0 * 32 + o) * 16 + m] + abuf[(1 * 32 + o) * 16 + m];
                mx = fmaxf(mx, fmaxf(s, 0.0f));
            }
        const f16x8 g = kan_feats8(mx);
        const size_t idx = ((b * 32 + o) * 14 + bh * 2 + hp) * 14 + bw * 2 + wp;
        *(u32x4*)(featP1 + idx * 4) = __builtin_bit_cast(u32x4, g);
    }
}

// L2 + fused head: gather 16B records + 72 MFMA steps (3-way K-split, atomicAdd h2);
// the LAST of the 75 blocks (completion counter) runs relu+avgpool+classifier.
__global__ __launch_bounds__(256, 4) void conv2_k(
    const unsigned int* __restrict__ fm, const _Float16* __restrict__ W2,
    float* __restrict__ h2, const float* __restrict__ wT,
    float* __restrict__ out, int* __restrict__ cnt) {
    __shared__ __align__(16) unsigned int featW[16 * 132];
    __shared__ int lastFlag;
    const int tid = threadIdx.x;
    const int task = blockIdx.x;
    const int ks = task % 3, rt = task / 3;
    const int lane = tid & 63, ot = tid >> 6;
    const int q = lane >> 4, l15 = lane & 15;
    const int ocol = ot * 16 + l15;
    const u32x4 F0p = __builtin_bit_cast(u32x4, kan_feats8(0.0f));
    const int i_in = tid & 31, rbase = tid >> 5;
    int hi0[2], wi0[2], pixb[2];
    bool rv[2];
#pragma unroll
    for (int t = 0; t < 2; ++t) {
        const int n = rt * 16 + rbase + t * 8;
        const int wo_ = n % 7, ho_ = (n / 7) % 7, b_ = n / 49;
        rv[t] = (n < 392);
        hi0[t] = ho_ * 2 - 1;
        wi0[t] = wo_ * 2 - 1;
        pixb[t] = b_ * 32 * 14 * 14;
    }
    f32x4 acc = {0.f, 0.f, 0.f, 0.f};
    const f16x8* __restrict__ Wv = (const f16x8*)W2;
    for (int c = ks * 3; c < ks * 3 + 3; ++c) {
        const int ii = c * 32 + i_in;
        const int ci = ii / 9, rem = ii - ci * 9;
        const int kh = rem / 3, kw = rem - kh * 3;
#pragma unroll
        for (int t = 0; t < 2; ++t) {
            const int hi = hi0[t] + kh, wi = wi0[t] + kw;
            const bool v = rv[t] && hi >= 0 && hi < 14 && wi >= 0 && wi < 14;
            u32x4 rec = F0p;
            if (v)
                rec = *(const u32x4*)(fm + (size_t)(pixb[t] + (ci * 14 + hi) * 14 + wi) * 4);
            *(u32x4*)(featW + (rbase + t * 8) * 132 + i_in * 4) = rec;
        }
        __syncthreads();
        const char* arow = (const char*)featW + l15 * 528 + q * 16;
#pragma unroll
        for (int s = 0; s < 8; ++s) {
            const f16x8 a = *(const f16x8*)(arow + s * 64);
            const f16x8 bf = Wv[(c * 32 + s * 4 + q) * 64 + ocol];
            acc = __builtin_amdgcn_mfma_f32_16x16x32_f16(a, bf, acc, 0, 0, 0);
        }
        __syncthreads();
    }
#pragma unroll
    for (int reg = 0; reg < 4; ++reg) {
        const int n = rt * 16 + q * 4 + reg;
        if (n < 392) {
            const int wo_ = n % 7, ho_ = (n / 7) % 7, b_ = n / 49;
            atomicAdd(h2 + ((b_ * 64 + ocol) * 7 + ho_) * 7 + wo_, acc[reg]);
        }
    }
    // ---- completion detection: last block runs the head ----
    __syncthreads();                 // all this block's atomics issued
    if (tid == 0) {
        __threadfence();             // release our h2 adds
        lastFlag = (atomicAdd(cnt, 1) == 74);
    }
    __syncthreads();
    if (!lastFlag) return;
    __threadfence();                 // acquire all blocks' h2 adds
    float* feat = (float*)featW;     // reuse LDS (>= 64*9 floats)
    for (int n = 0; n < 8; ++n) {
        if (tid < 64) {
            const float* p = h2 + (n * 64 + tid) * 49;
            float s = 0.0f;
            for (int j = 0; j < 49; ++j) s += fmaxf(p[j], 0.0f);
            float f9[9];
            kan_feats9(s / 49.0f, f9);
#pragma unroll
            for (int t = 0; t < 9; ++t) feat[tid * 9 + t] = f9[t];
        }
        __syncthreads();
        for (int o = tid; o < 200; o += 256) {
            float sum = 0.0f;
            for (int j = 0; j < 576; ++j) sum += feat[j] * wT[j * 200 + o];
            out[n * 200 + o] = sum;
        }
        __syncthreads();
    }
}

extern "C" void kernel_launch(void* const* d_in, const int* in_sizes, int n_in,
                              void* d_out, int out_size, void* d_ws, size_t ws_size,
                              hipStream_t stream) {
    const float* x   = (const float*)d_in[0];
    const float* bw0 = (const float*)d_in[1];
    const float* sw0 = (const float*)d_in[2];
    const float* sc0 = (const float*)d_in[3];
    const float* bw1 = (const float*)d_in[4];
    const float* sw1 = (const float*)d_in[5];
    const float* sc1 = (const float*)d_in[6];
    const float* bw2 = (const float*)d_in[7];
    const float* sw2 = (const float*)d_in[8];
    const float* sc2 = (const float*)d_in[9];
    const float* bwc = (const float*)d_in[10];
    const float* swc = (const float*)d_in[11];
    const float* scc = (const float*)d_in[12];
    float* out = (float*)d_out;

    char* ws = (char*)d_ws;
    size_t off = 0;
    auto alloc = [&](size_t nbytes) {
        char* p = ws + off;
        off += (nbytes + 255) & ~(size_t)255;
        return p;
    };
    _Float16* W2_0 = (_Float16*)alloc(PS0 * 16);
    _Float16* W2_1 = (_Float16*)alloc(PS1 * 16);
    _Float16* W2_2 = (_Float16*)alloc(PS2 * 16);
    float* wcT = (float*)alloc(576 * 200 * 4);
    float* h2  = (float*)alloc(8 * 64 * 49 * 4);   // dedicated (atomic target)
    int* cnt   = (int*)alloc(256);
    float* p0  = (float*)alloc((size_t)8 * 16 * 56 * 56 * 4);
    unsigned int* featP1 = (unsigned int*)alloc((size_t)8 * 32 * 14 * 14 * 16);

    prep_k<<<(PSUM + 256) / 256, 256, 0, stream>>>(
        bw0, sw0, sc0, bw1, sw1, sc1, bw2, sw2, sc2, bwc, swc, scc,
        W2_0, W2_1, W2_2, wcT, h2, cnt);
    conv0_k<<<1568, 256, 0, stream>>>(x, W2_0, p0);
    conv1_k<<<392, 256, 0, stream>>>(p0, W2_1, featP1);
    conv2_k<<<75, 256, 0, stream>>>(featP1, W2_2, h2, wcT, out, cnt);
}

// Round 12
// 132.578 us; speedup vs baseline: 1.5123x; 1.5123x over previous
//
#include <hip/hip_runtime.h>

#define DEV __device__ __forceinline__

typedef _Float16 f16x8 __attribute__((ext_vector_type(8)));
typedef float f32x4 __attribute__((ext_vector_type(4)));
typedef unsigned int u32x4 __attribute__((ext_vector_type(4)));

// Closed-form uniform cubic B-spline (knots (j-3)*0.4-1), verified vs Cox-de Boor (R9).
// All KAN-layer inputs are >= 0, so B_0,B_1 == 0. Record: [silu, B_2..B_7, 0].
DEV f16x8 kan_feats8(float x) {
    const float sil = x / (1.0f + __expf(-x));
    const float k0 = (float)(-3) * 0.4f - 1.0f;
    const float t = (x - k0) * 2.5f;
    const float mf = floorf(t);
    const int m = (int)mf;
    const float u = t - mf, v = 1.0f - u;
    const float u2 = u * u, u3 = u2 * u;
    const float N0 = v * v * v * (1.0f / 6.0f);
    const float N1 = (3.0f * u3 - 6.0f * u2 + 4.0f) * (1.0f / 6.0f);
    const float N2 = (-3.0f * u3 + 3.0f * u2 + 3.0f * u + 1.0f) * (1.0f / 6.0f);
    const float N3 = u3 * (1.0f / 6.0f);
    f16x8 g;
    g[0] = (_Float16)sil;
#pragma unroll
    for (int jj = 0; jj < 6; ++jj) {
        const int j = jj + 2;
        float val = 0.0f;
        val = (m == j + 3) ? N0 : val;
        val = (m == j + 2) ? N1 : val;
        val = (m == j + 1) ? N2 : val;
        val = (m == j)     ? N3 : val;
        g[1 + jj] = (_Float16)val;
    }
    g[7] = (_Float16)0.0f;
    return g;
}

// Full 9-feature version (head path).
DEV void kan_feats9(float x, float* f) {
    f[0] = x / (1.0f + __expf(-x));
    const float k0 = (float)(-3) * 0.4f - 1.0f;
    const float t = (x - k0) * 2.5f;
    const float mf = floorf(t);
    const int m = (int)mf;
    const float u = t - mf, v = 1.0f - u;
    const float u2 = u * u, u3 = u2 * u;
    const float N0 = v * v * v * (1.0f / 6.0f);
    const float N1 = (3.0f * u3 - 6.0f * u2 + 4.0f) * (1.0f / 6.0f);
    const float N2 = (-3.0f * u3 + 3.0f * u2 + 3.0f * u + 1.0f) * (1.0f / 6.0f);
    const float N3 = u3 * (1.0f / 6.0f);
#pragma unroll
    for (int j = 0; j < 8; ++j) {
        float val = 0.0f;
        val = (m == j + 3) ? N0 : val;
        val = (m == j + 2) ? N1 : val;
        val = (m == j + 1) ? N2 : val;
        val = (m == j)     ? N3 : val;
        f[1 + j] = val;
    }
}

// LDS A-plane byte offsets (pitch-8 records: one 16B octet per input).
__device__ constexpr int d_l0(int ii) {   // L0: (ci,kh,kw) over 3x7x7
    const int i = ii > 146 ? 146 : ii;    // i=147 zero-weight pad slot
    const int ci = i / 49, rem = i % 49, kh = rem / 7, kw = rem % 7;
    return ((((kw & 1) * 3 + ci) * 13 + kh) * 19 + (kw >> 1)) * 16;
}
__device__ constexpr int d_l1(int i) {    // L1: (ch,kh,kw) over 16x3x3
    const int ch = i / 9, rem = i % 9, kh = rem / 3, kw = rem % 3;
    return ((((kw & 1) * 16 + ch) * 9 + kh) * 5 + (kw >> 1)) * 16;
}

// Reduced weight octet: t=0 base, t=1..6 -> sw[j=t+1]*sc, t=7 = 0.
template <int OUT_F, int IN_F>
DEV void pack_oct8(int g, const float* bw, const float* sw, const float* sc,
                   _Float16* W2) {
    const int o = g % OUT_F, i = g / OUT_F;
    f16x8 v;
    if (i < IN_F) {
        const int wi = o * IN_F + i;
        const float s = sc[wi];
        v[0] = (_Float16)bw[wi];
#pragma unroll
        for (int t = 1; t <= 6; ++t) v[t] = (_Float16)(sw[wi * 8 + t + 1] * s);
        v[7] = (_Float16)0.0f;
    } else {
#pragma unroll
        for (int t = 0; t < 8; ++t) v[t] = (_Float16)0.0f;
    }
    *(f16x8*)(W2 + g * 8) = v;
}

#define PS0 2368   // L0: 148 koct * 16
#define PS1 4608   // L1: 144 koct * 32
#define PS2 18432  // L2: 288 koct * 64
#define PS3 12800  // head
#define PS4 25088  // h2 zero
#define PSUM (PS0 + PS1 + PS2 + PS3 + PS4)

__global__ __launch_bounds__(256) void prep_k(
    const float* __restrict__ bw0, const float* __restrict__ sw0, const float* __restrict__ sc0,
    const float* __restrict__ bw1, const float* __restrict__ sw1, const float* __restrict__ sc1,
    const float* __restrict__ bw2, const float* __restrict__ sw2, const float* __restrict__ sc2,
    const float* __restrict__ bwc, const float* __restrict__ swc, const float* __restrict__ scc,
    _Float16* __restrict__ W2_0, _Float16* __restrict__ W2_1, _Float16* __restrict__ W2_2,
    float* __restrict__ wcT, float* __restrict__ h2) {
    const int e = blockIdx.x * 256 + threadIdx.x;
    if (e < PS0) {
        pack_oct8<16, 147>(e, bw0, sw0, sc0, W2_0);
    } else if (e < PS0 + PS1) {
        pack_oct8<32, 144>(e - PS0, bw1, sw1, sc1, W2_1);
    } else if (e < PS0 + PS1 + PS2) {
        pack_oct8<64, 288>(e - PS0 - PS1, bw2, sw2, sc2, W2_2);
    } else if (e < PS0 + PS1 + PS2 + PS3) {
        const int ee = e - PS0 - PS1 - PS2;
        const int o = ee / 64, i = ee - o * 64;
        const float s = scc[ee];
        wcT[(i * 9 + 0) * 200 + o] = bwc[ee];
#pragma unroll
        for (int t = 0; t < 8; ++t)
            wcT[(i * 9 + 1 + t) * 200 + o] = swc[ee * 8 + t] * s;
    } else if (e < PSUM) {
        h2[e - PS0 - PS1 - PS2 - PS3] = 0.0f;
    }
}

// L0: featurize-in-block (pitch-8) + 37 MFMA steps + fused relu/2x2 pool -> raw p0.
// LDS 25760 B; request 5 blocks/CU for TLP.
__global__ __launch_bounds__(256, 5) void conv0_k(
    const float* __restrict__ x, const _Float16* __restrict__ W2,
    float* __restrict__ p0) {
    __shared__ __align__(16) _Float16 feats[1482 * 8];
    __shared__ float pb[4 * 8 * 16];
    const int tid = threadIdx.x;
    const int vt = blockIdx.x;
    const int b = vt / 196;
    const int r0 = vt - b * 196;
    const int bh = r0 / 7, bw = r0 - (r0 / 7) * 7;
    const int ih0 = bh * 8 - 3, iw0 = bw * 32 - 3;
    for (int t = tid; t < 1482; t += 256) {
        const int iwh = t % 19;
        int r = t / 19;
        const int ihp = r % 13; r /= 13;
        const int ci = r % 3;
        const int par = r / 3;
        const int ih = ih0 + ihp, iw = iw0 + 2 * iwh + par;
        float xv = 0.0f;
        if (ih >= 0 && ih < 224 && iw >= 0 && iw < 224)
            xv = x[((b * 3 + ci) * 224 + ih) * 224 + iw];
        *(f16x8*)(feats + t * 8) = kan_feats8(xv);
    }
    __syncthreads();
    const int lane = tid & 63, mt = tid >> 6;
    const int l15 = lane & 15, q = lane >> 4;
    const bool q1 = q & 1, q2 = q & 2;
    const char* aBase = (const char*)feats + ((2 * mt) * 19 + l15) * 16;
    const f16x8* __restrict__ Wv = (const f16x8*)W2;
    f32x4 acc = {0.f, 0.f, 0.f, 0.f};
#pragma unroll
    for (int s = 0; s < 37; ++s) {
        const int o0 = d_l0(4 * s), o1 = d_l0(4 * s + 1);
        const int o2 = d_l0(4 * s + 2), o3 = d_l0(4 * s + 3);
        const int e01 = q1 ? o1 : o0;
        const int e23 = q1 ? o3 : o2;
        const int aoff = q2 ? e23 : e01;
        const f16x8 a = *(const f16x8*)(aBase + aoff);
        const f16x8 bf = Wv[(s * 4 + q) * 16 + l15];
        acc = __builtin_amdgcn_mfma_f32_16x16x32_f16(a, bf, acc, 0, 0, 0);
    }
    pb[(mt * 8 + 2 * q + 0) * 16 + l15] = fmaxf(fmaxf(acc[0], 0.f), fmaxf(acc[1], 0.f));
    pb[(mt * 8 + 2 * q + 1) * 16 + l15] = fmaxf(fmaxf(acc[2], 0.f), fmaxf(acc[3], 0.f));
    __syncthreads();
    const int pr = tid >> 7, o = (tid >> 3) & 15, wp = tid & 7;
    const float v = fmaxf(pb[((2 * pr) * 8 + wp) * 16 + o],
                          pb[((2 * pr + 1) * 8 + wp) * 16 + o]);
    p0[((b * 16 + o) * 56 + bh * 2 + pr) * 56 + bw * 8 + wp] = v;
}

// L1: featurize-in-block + 36 MFMA steps (wave-pairs split K, LDS reduce) +
// fused relu/pool/featurize -> featP1 (16B records). LDS 27136 B; 5 blocks/CU.
__global__ __launch_bounds__(256, 5) void conv1_k(
    const float* __restrict__ p0, const _Float16* __restrict__ W2,
    unsigned int* __restrict__ featP1) {
    __shared__ __align__(16) _Float16 feats[1440 * 8];
    __shared__ float abuf[2 * 32 * 16];
    const int tid = threadIdx.x;
    const int vt = blockIdx.x;
    const int b = vt / 49;
    const int r0 = vt - b * 49;
    const int bh = r0 / 7, bw = r0 - (r0 / 7) * 7;
    const int ih0 = bh * 8 - 1, iw0 = bw * 8 - 1;
    for (int t = tid; t < 1296; t += 256) {
        const int iwp = t % 9;
        int r = t / 9;
        const int ihp = r % 9;
        const int ch = r / 9;
        const int ih = ih0 + ihp, iw = iw0 + iwp;
        float xv = 0.0f;
        if (ih >= 0 && ih < 56 && iw >= 0 && iw < 56)
            xv = p0[((b * 16 + ch) * 56 + ih) * 56 + iw];
        const int slot = (((iwp & 1) * 16 + ch) * 9 + ihp) * 5 + (iwp >> 1);
        *(f16x8*)(feats + slot * 8) = kan_feats8(xv);
    }
    __syncthreads();
    const int lane = tid & 63, w = tid >> 6;
    const int kc = w >> 1, ot = w & 1;
    const int l15 = lane & 15, q = lane >> 4;
    const bool q1 = q & 1, q2 = q & 2;
    const int mh = l15 >> 2, mw = l15 & 3;
    const int ocol = ot * 16 + l15;
    const char* aBase = (const char*)feats + ((2 * mh) * 5 + mw) * 16 + kc * 5760;
    const f16x8* __restrict__ Wv = (const f16x8*)W2;
    f32x4 acc = {0.f, 0.f, 0.f, 0.f};
#pragma unroll
    for (int s = 0; s < 18; ++s) {
        const int o0 = d_l1(4 * s), o1 = d_l1(4 * s + 1);
        const int o2 = d_l1(4 * s + 2), o3 = d_l1(4 * s + 3);
        const int e01 = q1 ? o1 : o0;
        const int e23 = q1 ? o3 : o2;
        const int aoff = q2 ? e23 : e01;
        const f16x8 a = *(const f16x8*)(aBase + aoff);
        const f16x8 bf = Wv[(kc * 72 + s * 4 + q) * 32 + ocol];
        acc = __builtin_amdgcn_mfma_f32_16x16x32_f16(a, bf, acc, 0, 0, 0);
    }
#pragma unroll
    for (int reg = 0; reg < 4; ++reg)
        abuf[(kc * 32 + ocol) * 16 + q * 4 + reg] = acc[reg];
    __syncthreads();
    if (tid < 128) {
        const int o = tid >> 2, pp = tid & 3;
        const int hp = pp >> 1, wp = pp & 1;
        float mx = -1e30f;
#pragma unroll
        for (int dh = 0; dh < 2; ++dh)
#pragma unroll
            for (int dw = 0; dw < 2; ++dw) {
                const int m = (2 * hp + dh) * 4 + 2 * wp + dw;
                const float s = abuf[(0 * 32 + o) * 16 + m] + abuf[(1 * 32 + o) * 16 + m];
                mx = fmaxf(mx, fmaxf(s, 0.0f));
            }
        const f16x8 g = kan_feats8(mx);
        const size_t idx = ((b * 32 + o) * 14 + bh * 2 + hp) * 14 + bw * 2 + wp;
        *(u32x4*)(featP1 + idx * 4) = __builtin_bit_cast(u32x4, g);
    }
}

// L2: gather 16B records + 72 MFMA steps (3-way K-split, atomicAdd h2). LDS 8448 B.
__global__ __launch_bounds__(256, 4) void conv2_k(
    const unsigned int* __restrict__ fm, const _Float16* __restrict__ W2,
    float* __restrict__ h2) {
    __shared__ __align__(16) unsigned int featW[16 * 132];
    const int tid = threadIdx.x;
    const int task = blockIdx.x;
    const int ks = task % 3, rt = task / 3;
    const int lane = tid & 63, ot = tid >> 6;
    const int q = lane >> 4, l15 = lane & 15;
    const int ocol = ot * 16 + l15;
    const u32x4 F0p = __builtin_bit_cast(u32x4, kan_feats8(0.0f));
    const int i_in = tid & 31, rbase = tid >> 5;
    int hi0[2], wi0[2], pixb[2];
    bool rv[2];
#pragma unroll
    for (int t = 0; t < 2; ++t) {
        const int n = rt * 16 + rbase + t * 8;
        const int wo_ = n % 7, ho_ = (n / 7) % 7, b_ = n / 49;
        rv[t] = (n < 392);
        hi0[t] = ho_ * 2 - 1;
        wi0[t] = wo_ * 2 - 1;
        pixb[t] = b_ * 32 * 14 * 14;
    }
    f32x4 acc = {0.f, 0.f, 0.f, 0.f};
    const f16x8* __restrict__ Wv = (const f16x8*)W2;
    for (int c = ks * 3; c < ks * 3 + 3; ++c) {
        const int ii = c * 32 + i_in;
        const int ci = ii / 9, rem = ii - ci * 9;
        const int kh = rem / 3, kw = rem - kh * 3;
#pragma unroll
        for (int t = 0; t < 2; ++t) {
            const int hi = hi0[t] + kh, wi = wi0[t] + kw;
            const bool v = rv[t] && hi >= 0 && hi < 14 && wi >= 0 && wi < 14;
            u32x4 rec = F0p;
            if (v)
                rec = *(const u32x4*)(fm + (size_t)(pixb[t] + (ci * 14 + hi) * 14 + wi) * 4);
            *(u32x4*)(featW + (rbase + t * 8) * 132 + i_in * 4) = rec;
        }
        __syncthreads();
        const char* arow = (const char*)featW + l15 * 528 + q * 16;
#pragma unroll
        for (int s = 0; s < 8; ++s) {
            const f16x8 a = *(const f16x8*)(arow + s * 64);
            const f16x8 bf = Wv[(c * 32 + s * 4 + q) * 64 + ocol];
            acc = __builtin_amdgcn_mfma_f32_16x16x32_f16(a, bf, acc, 0, 0, 0);
        }
        __syncthreads();
    }
#pragma unroll
    for (int reg = 0; reg < 4; ++reg) {
        const int n = rt * 16 + q * 4 + reg;
        if (n < 392) {
            const int wo_ = n % 7, ho_ = (n / 7) % 7, b_ = n / 49;
            atomicAdd(h2 + ((b_ * 64 + ocol) * 7 + ho_) * 7 + wo_, acc[reg]);
        }
    }
}

// relu + global-avg-pool + fp32 classifier (full 9-feature path). 8 blocks.
__global__ __launch_bounds__(256) void head_k(
    const float* __restrict__ h2, const float* __restrict__ wT,
    float* __restrict__ out) {
    __shared__ float feat[64 * 9];
    const int n = blockIdx.x;
    const int tid = threadIdx.x;
    if (tid < 64) {
        const float* p = h2 + (n * 64 + tid) * 49;
        float s = 0.0f;
        for (int j = 0; j < 49; ++j) s += fmaxf(p[j], 0.0f);
        float f9[9];
        kan_feats9(s / 49.0f, f9);
#pragma unroll
        for (int t = 0; t < 9; ++t) feat[tid * 9 + t] = f9[t];
    }
    __syncthreads();
    for (int o = tid; o < 200; o += 256) {
        float sum = 0.0f;
        for (int j = 0; j < 576; ++j) sum += feat[j] * wT[j * 200 + o];
        out[n * 200 + o] = sum;
    }
}

extern "C" void kernel_launch(void* const* d_in, const int* in_sizes, int n_in,
                              void* d_out, int out_size, void* d_ws, size_t ws_size,
                              hipStream_t stream) {
    const float* x   = (const float*)d_in[0];
    const float* bw0 = (const float*)d_in[1];
    const float* sw0 = (const float*)d_in[2];
    const float* sc0 = (const float*)d_in[3];
    const float* bw1 = (const float*)d_in[4];
    const float* sw1 = (const float*)d_in[5];
    const float* sc1 = (const float*)d_in[6];
    const float* bw2 = (const float*)d_in[7];
    const float* sw2 = (const float*)d_in[8];
    const float* sc2 = (const float*)d_in[9];
    const float* bwc = (const float*)d_in[10];
    const float* swc = (const float*)d_in[11];
    const float* scc = (const float*)d_in[12];
    float* out = (float*)d_out;

    char* ws = (char*)d_ws;
    size_t off = 0;
    auto alloc = [&](size_t nbytes) {
        char* p = ws + off;
        off += (nbytes + 255) & ~(size_t)255;
        return p;
    };
    _Float16* W2_0 = (_Float16*)alloc(PS0 * 16);
    _Float16* W2_1 = (_Float16*)alloc(PS1 * 16);
    _Float16* W2_2 = (_Float16*)alloc(PS2 * 16);
    float* wcT = (float*)alloc(576 * 200 * 4);
    float* h2  = (float*)alloc(8 * 64 * 49 * 4);   // dedicated (atomic target)
    float* p0  = (float*)alloc((size_t)8 * 16 * 56 * 56 * 4);
    unsigned int* featP1 = (unsigned int*)alloc((size_t)8 * 32 * 14 * 14 * 16);

    prep_k<<<(PSUM + 255) / 256, 256, 0, stream>>>(
        bw0, sw0, sc0, bw1, sw1, sc1, bw2, sw2, sc2, bwc, swc, scc,
        W2_0, W2_1, W2_2, wcT, h2);
    conv0_k<<<1568, 256, 0, stream>>>(x, W2_0, p0);
    conv1_k<<<392, 256, 0, stream>>>(p0, W2_1, featP1);
    conv2_k<<<75, 256, 0, stream>>>(featP1, W2_2, h2);
    head_k<<<8, 256, 0, stream>>>(h2, wcT, out);
}